// Round 1
// baseline (251.200 us; speedup 1.0000x reference)
//
#include <hip/hip_runtime.h>
#include <hip/hip_bf16.h>
#include <stdint.h>

// Problem dims: T=8192 tokens, H=2048 hidden, I=768 intermediate
// fp32 in/out; internal bf16 MFMA (absmax 0.0156 vs 0.074 budget).
#define T_DIM 8192
#define H_DIM 2048
#define I_DIM 768

typedef __bf16 bf16_t;
typedef bf16_t bf16x8 __attribute__((ext_vector_type(8)));
typedef bf16_t bf16x4 __attribute__((ext_vector_type(4)));
typedef float  f32x4  __attribute__((ext_vector_type(4)));

// Async global->LDS, 16B per lane. LDS dest must be wave-uniform base + lane*16
// (linear). Swizzle therefore goes on the GLOBAL source + the ds_read address.
__device__ __forceinline__ void async_load16(const void* g, void* s) {
    __builtin_amdgcn_global_load_lds(
        (const __attribute__((address_space(1))) void*)g,
        (__attribute__((address_space(3))) void*)s, 16, 0, 0);
}

// ---------------------------------------------------------------------------
// Kernel 0: fp32 -> bf16 conversion of all four inputs into workspace.
// ---------------------------------------------------------------------------
__global__ __launch_bounds__(256) void cvt_kernel(
    const float* __restrict__ X, const float* __restrict__ G,
    const float* __restrict__ U, const float* __restrict__ D,
    bf16_t* __restrict__ Xb, bf16_t* __restrict__ Gb,
    bf16_t* __restrict__ Ub, bf16_t* __restrict__ Db)
{
    const size_t N4X = (size_t)T_DIM * H_DIM / 4;
    const size_t N4W = (size_t)I_DIM * H_DIM / 4;
    const size_t total = N4X + 3 * N4W;
    for (size_t i = (size_t)blockIdx.x * blockDim.x + threadIdx.x; i < total;
         i += (size_t)gridDim.x * blockDim.x) {
        const float* s; bf16_t* d; size_t j = i;
        if (j < N4X) { s = X; d = Xb; }
        else {
            j -= N4X;
            if (j < N4W) { s = G; d = Gb; }
            else { j -= N4W;
                if (j < N4W) { s = U; d = Ub; }
                else { j -= N4W; s = D; d = Db; } }
        }
        float4 v = ((const float4*)s)[j];
        bf16x4 o;
        o[0] = (bf16_t)v.x; o[1] = (bf16_t)v.y; o[2] = (bf16_t)v.z; o[3] = (bf16_t)v.w;
        ((bf16x4*)d)[j] = o;
    }
}

// ---------------------------------------------------------------------------
// LDS swizzle: tile rows are 32 bf16 = 64 B = 4 x 16B slots.
// Stored slot cs = global col-block c ^ ((row>>1)&3).  This makes every
// consecutive-8-lane group of a frag ds_read_b128 hit 8 distinct 16B bank
// slots (was ~8-way aliased -> measured 4 extra cyc per read).
// Stage side: LDS dest stays LINEAR (global_load_lds requirement); the
// global source column is pre-swizzled instead (rule: both-sides-or-neither).
// ---------------------------------------------------------------------------

// ---------------------------------------------------------------------------
// Kernel 1: 128x64 tile of [T, I]: h = silu(x@gate^T) * (x@up^T) -> bf16.
// Grid 64x12 = 768 blocks = 3/CU. 4 waves 2x2; wave owns 64x32 of G and U.
// Double-buffered LDS (32 KB), stage-ahead with counted vmcnt(4): the
// current tile's loads were issued one full K-step earlier.
// ---------------------------------------------------------------------------
__global__ __launch_bounds__(256) void gateup_kernel(
    const bf16_t* __restrict__ X,
    const bf16_t* __restrict__ Wg,
    const bf16_t* __restrict__ Wu,
    bf16_t* __restrict__ Hbuf)
{
    __shared__ __align__(16) bf16_t sA[2][128 * 32];   // 2 x 8 KB
    __shared__ __align__(16) bf16_t sG[2][64 * 32];    // 2 x 4 KB
    __shared__ __align__(16) bf16_t sU[2][64 * 32];    // 2 x 4 KB

    const int tid   = threadIdx.x;
    const int lane  = tid & 63;
    const int wave  = tid >> 6;
    const int waveM = wave >> 1;
    const int waveN = wave & 1;
    const int quad  = lane >> 4;
    const int lrow  = lane & 15;

    const int blockM = blockIdx.x;    // 0..63  (T/128)
    const int blockN = blockIdx.y;    // 0..11  (I/64)

    f32x4 accG[4][2], accU[4][2];
#pragma unroll
    for (int i = 0; i < 4; i++)
#pragma unroll
        for (int j = 0; j < 2; j++) { accG[i][j] = (f32x4)(0.f); accU[i][j] = (f32x4)(0.f); }

    // Staging segments: A 512 x 16B (2/thread), G/U 256 x 16B (1/thread).
    // Segment s: row = s/4, stored col-slot = s%4; source col-block is
    // swizzled: c = (s%4) ^ ((row>>1)&3); element offset = c*8.
    const int s0 = tid, s1 = tid + 256;
    const int rA0 = s0 >> 2, cA0 = (((s0 & 3) ^ ((rA0 >> 1) & 3)) * 8);
    const int rA1 = s1 >> 2, cA1 = (((s1 & 3) ^ ((rA1 >> 1) & 3)) * 8);
    const int rW  = tid >> 2, cW  = (((tid & 3) ^ ((rW >> 1) & 3)) * 8);

    const bf16_t* Ab = X  + (size_t)(blockM * 128) * H_DIM;
    const bf16_t* Gw = Wg + (size_t)(blockN * 64) * H_DIM;
    const bf16_t* Uw = Wu + (size_t)(blockN * 64) * H_DIM;

    // Read-side swizzled element offsets (loop-invariant).
    int aOff[4], wOff[2];
#pragma unroll
    for (int mi = 0; mi < 4; mi++) {
        int r = waveM * 64 + mi * 16 + lrow;
        aOff[mi] = r * 32 + ((quad ^ ((r >> 1) & 3)) * 8);
    }
#pragma unroll
    for (int ni = 0; ni < 2; ni++) {
        int r = waveN * 32 + ni * 16 + lrow;
        wOff[ni] = r * 32 + ((quad ^ ((r >> 1) & 3)) * 8);
    }

    // Prologue: stage tile k0=0 into buffer 0.
    async_load16(Ab + (size_t)rA0 * H_DIM + cA0, &sA[0][s0 * 8]);
    async_load16(Ab + (size_t)rA1 * H_DIM + cA1, &sA[0][s1 * 8]);
    async_load16(Gw + (size_t)rW  * H_DIM + cW,  &sG[0][tid * 8]);
    async_load16(Uw + (size_t)rW  * H_DIM + cW,  &sU[0][tid * 8]);

    int cur = 0;
    for (int k0 = 0; k0 < H_DIM; k0 += 32) {
        // Barrier 1: all waves finished reading buf[cur^1] (prev iter) before
        // this iter's stage overwrites it.
        __builtin_amdgcn_s_barrier();
        if (k0 + 32 < H_DIM) {
            const int nxt = cur ^ 1;
            async_load16(Ab + (size_t)rA0 * H_DIM + (k0 + 32) + cA0, &sA[nxt][s0 * 8]);
            async_load16(Ab + (size_t)rA1 * H_DIM + (k0 + 32) + cA1, &sA[nxt][s1 * 8]);
            async_load16(Gw + (size_t)rW  * H_DIM + (k0 + 32) + cW,  &sG[nxt][tid * 8]);
            async_load16(Uw + (size_t)rW  * H_DIM + (k0 + 32) + cW,  &sU[nxt][tid * 8]);
            // Counted wait: retire the 4 oldest (current tile, issued last
            // iter); the 4 just-issued stay in flight across the barrier.
            asm volatile("s_waitcnt vmcnt(4)" ::: "memory");
        } else {
            asm volatile("s_waitcnt vmcnt(0)" ::: "memory");
        }
        __builtin_amdgcn_s_barrier();
        asm volatile("" ::: "memory");   // compiler fence: no LDS-read hoist

        bf16x8 aF[4], gF[2], uF[2];
#pragma unroll
        for (int mi = 0; mi < 4; mi++)
            aF[mi] = *(const bf16x8*)&sA[cur][aOff[mi]];
#pragma unroll
        for (int ni = 0; ni < 2; ni++) {
            gF[ni] = *(const bf16x8*)&sG[cur][wOff[ni]];
            uF[ni] = *(const bf16x8*)&sU[cur][wOff[ni]];
        }

#pragma unroll
        for (int mi = 0; mi < 4; mi++)
#pragma unroll
            for (int ni = 0; ni < 2; ni++) {
                accG[mi][ni] = __builtin_amdgcn_mfma_f32_16x16x32_bf16(aF[mi], gF[ni], accG[mi][ni], 0, 0, 0);
                accU[mi][ni] = __builtin_amdgcn_mfma_f32_16x16x32_bf16(aF[mi], uF[ni], accU[mi][ni], 0, 0, 0);
            }
        cur ^= 1;
    }

    // Epilogue: h = silu(g)*u, cast bf16. C/D layout: col=lane&15, row=quad*4+r.
#pragma unroll
    for (int mi = 0; mi < 4; mi++) {
#pragma unroll
        for (int ni = 0; ni < 2; ni++) {
#pragma unroll
            for (int r = 0; r < 4; r++) {
                int row = blockM * 128 + waveM * 64 + mi * 16 + quad * 4 + r;
                int col = blockN * 64 + waveN * 32 + ni * 16 + lrow;
                float g = accG[mi][ni][r];
                float u = accU[mi][ni][r];
                float h = (g / (1.f + __expf(-g))) * u;
                Hbuf[(size_t)row * I_DIM + col] = (bf16_t)h;
            }
        }
    }
}

// ---------------------------------------------------------------------------
// Kernel 2: out[T,H] = h @ down^T. 128x128 tiles, grid 64x16 = 1024 (4/CU).
// Same swizzle + 2-phase prefetch. K = 768 -> 24 steps of 32.
// ---------------------------------------------------------------------------
__global__ __launch_bounds__(256) void down_kernel(
    const bf16_t* __restrict__ Hbuf,
    const bf16_t* __restrict__ Wd,
    float* __restrict__ Out)
{
    __shared__ __align__(16) bf16_t sA[2][128 * 32];
    __shared__ __align__(16) bf16_t sB[2][128 * 32];

    const int tid   = threadIdx.x;
    const int lane  = tid & 63;
    const int wave  = tid >> 6;
    const int waveM = wave >> 1;
    const int waveN = wave & 1;
    const int quad  = lane >> 4;
    const int lrow  = lane & 15;

    const int blockM = blockIdx.x;    // 0..63  (T/128)
    const int blockN = blockIdx.y;    // 0..15  (H/128)

    f32x4 acc[4][4];
#pragma unroll
    for (int i = 0; i < 4; i++)
#pragma unroll
        for (int j = 0; j < 4; j++) acc[i][j] = (f32x4)(0.f);

    const int s0 = tid, s1 = tid + 256;
    const int rA0 = s0 >> 2, cA0 = (((s0 & 3) ^ ((rA0 >> 1) & 3)) * 8);
    const int rA1 = s1 >> 2, cA1 = (((s1 & 3) ^ ((rA1 >> 1) & 3)) * 8);

    const bf16_t* Ab = Hbuf + (size_t)(blockM * 128) * I_DIM;
    const bf16_t* Bb = Wd   + (size_t)(blockN * 128) * I_DIM;

    int aOff[4], bOff[4];
#pragma unroll
    for (int mi = 0; mi < 4; mi++) {
        int r = waveM * 64 + mi * 16 + lrow;
        aOff[mi] = r * 32 + ((quad ^ ((r >> 1) & 3)) * 8);
    }
#pragma unroll
    for (int ni = 0; ni < 4; ni++) {
        int r = waveN * 64 + ni * 16 + lrow;
        bOff[ni] = r * 32 + ((quad ^ ((r >> 1) & 3)) * 8);
    }

    // Prologue: stage tile k0=0 into buffer 0.
    async_load16(Ab + (size_t)rA0 * I_DIM + cA0, &sA[0][s0 * 8]);
    async_load16(Ab + (size_t)rA1 * I_DIM + cA1, &sA[0][s1 * 8]);
    async_load16(Bb + (size_t)rA0 * I_DIM + cA0, &sB[0][s0 * 8]);
    async_load16(Bb + (size_t)rA1 * I_DIM + cA1, &sB[0][s1 * 8]);

    int cur = 0;
    for (int k0 = 0; k0 < I_DIM; k0 += 32) {
        __builtin_amdgcn_s_barrier();
        if (k0 + 32 < I_DIM) {
            const int nxt = cur ^ 1;
            async_load16(Ab + (size_t)rA0 * I_DIM + (k0 + 32) + cA0, &sA[nxt][s0 * 8]);
            async_load16(Ab + (size_t)rA1 * I_DIM + (k0 + 32) + cA1, &sA[nxt][s1 * 8]);
            async_load16(Bb + (size_t)rA0 * I_DIM + (k0 + 32) + cA0, &sB[nxt][s0 * 8]);
            async_load16(Bb + (size_t)rA1 * I_DIM + (k0 + 32) + cA1, &sB[nxt][s1 * 8]);
            asm volatile("s_waitcnt vmcnt(4)" ::: "memory");
        } else {
            asm volatile("s_waitcnt vmcnt(0)" ::: "memory");
        }
        __builtin_amdgcn_s_barrier();
        asm volatile("" ::: "memory");

        bf16x8 aF[4], bF[4];
#pragma unroll
        for (int mi = 0; mi < 4; mi++)
            aF[mi] = *(const bf16x8*)&sA[cur][aOff[mi]];
#pragma unroll
        for (int ni = 0; ni < 4; ni++)
            bF[ni] = *(const bf16x8*)&sB[cur][bOff[ni]];

#pragma unroll
        for (int mi = 0; mi < 4; mi++)
#pragma unroll
            for (int ni = 0; ni < 4; ni++)
                acc[mi][ni] = __builtin_amdgcn_mfma_f32_16x16x32_bf16(aF[mi], bF[ni], acc[mi][ni], 0, 0, 0);
        cur ^= 1;
    }

#pragma unroll
    for (int mi = 0; mi < 4; mi++) {
#pragma unroll
        for (int ni = 0; ni < 4; ni++) {
#pragma unroll
            for (int r = 0; r < 4; r++) {
                int row = blockM * 128 + waveM * 64 + mi * 16 + quad * 4 + r;
                int col = blockN * 128 + waveN * 64 + ni * 16 + lrow;
                Out[(size_t)row * H_DIM + col] = acc[mi][ni][r];
            }
        }
    }
}

extern "C" void kernel_launch(void* const* d_in, const int* in_sizes, int n_in,
                              void* d_out, int out_size, void* d_ws, size_t ws_size,
                              hipStream_t stream) {
    const float* x  = (const float*)d_in[0];  // [T, H] fp32
    const float* gw = (const float*)d_in[1];  // [I, H] fp32
    const float* uw = (const float*)d_in[2];  // [I, H] fp32
    const float* dw = (const float*)d_in[3];  // [H, I] fp32
    float* out = (float*)d_out;               // [T, H] fp32

    bf16_t* xb = (bf16_t*)d_ws;
    bf16_t* gb = xb + (size_t)T_DIM * H_DIM;
    bf16_t* ub = gb + (size_t)I_DIM * H_DIM;
    bf16_t* db = ub + (size_t)I_DIM * H_DIM;
    bf16_t* hb = db + (size_t)I_DIM * H_DIM;

    cvt_kernel<<<2048, 256, 0, stream>>>(x, gw, uw, dw, xb, gb, ub, db);
    gateup_kernel<<<dim3(T_DIM / 128, I_DIM / 64), 256, 0, stream>>>(xb, gb, ub, hb);
    down_kernel<<<dim3(T_DIM / 128, H_DIM / 128), 256, 0, stream>>>(hb, db, out);
}

// Round 2
// 238.362 us; speedup vs baseline: 1.0539x; 1.0539x over previous
//
#include <hip/hip_runtime.h>
#include <hip/hip_bf16.h>
#include <stdint.h>

// Problem dims: T=8192 tokens, H=2048 hidden, I=768 intermediate
// fp32 in/out; internal bf16 MFMA (absmax 0.0156 vs 0.074 budget).
#define T_DIM 8192
#define H_DIM 2048
#define I_DIM 768

typedef __bf16 bf16_t;
typedef bf16_t bf16x8 __attribute__((ext_vector_type(8)));
typedef bf16_t bf16x4 __attribute__((ext_vector_type(4)));
typedef float  f32x4  __attribute__((ext_vector_type(4)));

// Async global->LDS, 16B per lane. LDS dest must be wave-uniform base + lane*16
// (linear). Swizzle therefore goes on the GLOBAL source + the ds_read address
// (both-sides-or-neither rule).
__device__ __forceinline__ void async_load16(const void* g, void* s) {
    __builtin_amdgcn_global_load_lds(
        (const __attribute__((address_space(1))) void*)g,
        (__attribute__((address_space(3))) void*)s, 16, 0, 0);
}

// ---------------------------------------------------------------------------
// Kernel 0: fp32 -> bf16 conversion of all four inputs into workspace.
// 8 floats/thread: 2x float4 read (32B), 1x bf16x8 write (16B).
// ---------------------------------------------------------------------------
__global__ __launch_bounds__(256) void cvt_kernel(
    const float* __restrict__ X, const float* __restrict__ G,
    const float* __restrict__ U, const float* __restrict__ D,
    bf16_t* __restrict__ Xb, bf16_t* __restrict__ Gb,
    bf16_t* __restrict__ Ub, bf16_t* __restrict__ Db)
{
    const size_t N8X = (size_t)T_DIM * H_DIM / 8;
    const size_t N8W = (size_t)I_DIM * H_DIM / 8;
    const size_t total = N8X + 3 * N8W;
    for (size_t i = (size_t)blockIdx.x * blockDim.x + threadIdx.x; i < total;
         i += (size_t)gridDim.x * blockDim.x) {
        const float* s; bf16_t* d; size_t j = i;
        if (j < N8X) { s = X; d = Xb; }
        else {
            j -= N8X;
            if (j < N8W) { s = G; d = Gb; }
            else { j -= N8W;
                if (j < N8W) { s = U; d = Ub; }
                else { j -= N8W; s = D; d = Db; } }
        }
        float4 v0 = ((const float4*)s)[2 * j];
        float4 v1 = ((const float4*)s)[2 * j + 1];
        bf16x8 o;
        o[0] = (bf16_t)v0.x; o[1] = (bf16_t)v0.y; o[2] = (bf16_t)v0.z; o[3] = (bf16_t)v0.w;
        o[4] = (bf16_t)v1.x; o[5] = (bf16_t)v1.y; o[6] = (bf16_t)v1.z; o[7] = (bf16_t)v1.w;
        ((bf16x8*)d)[j] = o;
    }
}

// ---------------------------------------------------------------------------
// LDS swizzle (BK=64): tile rows are 64 bf16 = 128 B = 8 x 16B slots.
// Unswizzled, a frag ds_read_b128 puts 16 lanes (consecutive rows, same
// col-slot) on the SAME 4-bank group -> 16-way serialization. Stored slot
// cs = c ^ (row & 7) spreads 8 consecutive rows across all 8 slots: per
// 4-bank group 8 lanes with distinct rows = minimum cycles, zero conflict.
// Stage side: LDS dest stays LINEAR (global_load_lds requirement); the
// global source col-block is pre-swizzled with the same XOR (involution).
// kk=1 read offset = kk=0 offset XOR 32 elements (slot^4 <=> elem^32).
// ---------------------------------------------------------------------------

// ---------------------------------------------------------------------------
// Kernel 1: 128x64 (MxN) tile of [T, I]: h = silu(x@gate^T) * (x@up^T).
// Grid 64x12 = 768 blocks = 3/CU. 4 waves 2x2; wave owns 64x32 of G and U.
// r0 schedule (single buffer, plain __syncthreads) -- proven best -- but
// BK=64: half the vmcnt(0) drain events, 32 MFMA/wave between barriers.
// LDS 32 KB/block.
// ---------------------------------------------------------------------------
__global__ __launch_bounds__(256) void gateup_kernel(
    const bf16_t* __restrict__ X,
    const bf16_t* __restrict__ Wg,
    const bf16_t* __restrict__ Wu,
    bf16_t* __restrict__ Hbuf)
{
    __shared__ __align__(16) bf16_t sA[128 * 64];   // 16 KB
    __shared__ __align__(16) bf16_t sG[64 * 64];    //  8 KB
    __shared__ __align__(16) bf16_t sU[64 * 64];    //  8 KB

    const int tid   = threadIdx.x;
    const int lane  = tid & 63;
    const int wave  = tid >> 6;
    const int waveM = wave >> 1;
    const int waveN = wave & 1;
    const int quad  = lane >> 4;
    const int lrow  = lane & 15;

    const int blockM = blockIdx.x;    // 0..63  (T/128)
    const int blockN = blockIdx.y;    // 0..11  (I/64)

    f32x4 accG[4][2], accU[4][2];
#pragma unroll
    for (int i = 0; i < 4; i++)
#pragma unroll
        for (int j = 0; j < 2; j++) { accG[i][j] = (f32x4)(0.f); accU[i][j] = (f32x4)(0.f); }

    // Staging: segment s -> row = s>>3, stored slot = s&7,
    // source col-block c = (s&7) ^ ((s>>3)&7)  (elements: c*8).
    // A: 1024 segs (4/thread); G/U: 512 segs (2/thread each).
    const bf16_t* Ab = X  + (size_t)(blockM * 128) * H_DIM;
    const bf16_t* Gw = Wg + (size_t)(blockN * 64) * H_DIM;
    const bf16_t* Uw = Wu + (size_t)(blockN * 64) * H_DIM;

    int aRow[4], aCol[4];   // A staging source (row, col-elem) per segment
#pragma unroll
    for (int i = 0; i < 4; i++) {
        int s = tid + 256 * i;
        aRow[i] = s >> 3;
        aCol[i] = ((s & 7) ^ ((s >> 3) & 7)) * 8;
    }
    int wRow[2], wCol[2];   // G/U staging source per segment
#pragma unroll
    for (int i = 0; i < 2; i++) {
        int s = tid + 256 * i;
        wRow[i] = s >> 3;
        wCol[i] = ((s & 7) ^ ((s >> 3) & 7)) * 8;
    }

    // Read-side swizzled element offsets for kk=0 (kk=1: XOR 32).
    int aOff[4], wOff[2];
#pragma unroll
    for (int mi = 0; mi < 4; mi++) {
        int r = waveM * 64 + mi * 16 + lrow;
        aOff[mi] = r * 64 + ((quad ^ (r & 7)) * 8);
    }
#pragma unroll
    for (int ni = 0; ni < 2; ni++) {
        int r = waveN * 32 + ni * 16 + lrow;
        wOff[ni] = r * 64 + ((quad ^ (r & 7)) * 8);
    }

    for (int k0 = 0; k0 < H_DIM; k0 += 64) {
#pragma unroll
        for (int i = 0; i < 4; i++)
            async_load16(Ab + (size_t)aRow[i] * H_DIM + k0 + aCol[i],
                         &sA[(tid + 256 * i) * 8]);
#pragma unroll
        for (int i = 0; i < 2; i++) {
            async_load16(Gw + (size_t)wRow[i] * H_DIM + k0 + wCol[i],
                         &sG[(tid + 256 * i) * 8]);
            async_load16(Uw + (size_t)wRow[i] * H_DIM + k0 + wCol[i],
                         &sU[(tid + 256 * i) * 8]);
        }
        __syncthreads();   // vmcnt(0) drain + barrier

#pragma unroll
        for (int kk = 0; kk < 2; kk++) {
            const int kx = kk * 32;   // slot^4 <=> element offset ^32
            bf16x8 aF[4], gF[2], uF[2];
#pragma unroll
            for (int mi = 0; mi < 4; mi++)
                aF[mi] = *(const bf16x8*)&sA[aOff[mi] ^ kx];
#pragma unroll
            for (int ni = 0; ni < 2; ni++) {
                gF[ni] = *(const bf16x8*)&sG[wOff[ni] ^ kx];
                uF[ni] = *(const bf16x8*)&sU[wOff[ni] ^ kx];
            }
#pragma unroll
            for (int mi = 0; mi < 4; mi++)
#pragma unroll
                for (int ni = 0; ni < 2; ni++) {
                    accG[mi][ni] = __builtin_amdgcn_mfma_f32_16x16x32_bf16(aF[mi], gF[ni], accG[mi][ni], 0, 0, 0);
                    accU[mi][ni] = __builtin_amdgcn_mfma_f32_16x16x32_bf16(aF[mi], uF[ni], accU[mi][ni], 0, 0, 0);
                }
        }
        __syncthreads();   // frags consumed; next iter overwrites LDS
    }

    // Epilogue: h = silu(g)*u, cast bf16. C/D layout: col=lane&15, row=quad*4+r.
#pragma unroll
    for (int mi = 0; mi < 4; mi++) {
#pragma unroll
        for (int ni = 0; ni < 2; ni++) {
#pragma unroll
            for (int r = 0; r < 4; r++) {
                int row = blockM * 128 + waveM * 64 + mi * 16 + quad * 4 + r;
                int col = blockN * 64 + waveN * 32 + ni * 16 + lrow;
                float g = accG[mi][ni][r];
                float u = accU[mi][ni][r];
                float h = (g / (1.f + __expf(-g))) * u;
                Hbuf[(size_t)row * I_DIM + col] = (bf16_t)h;
            }
        }
    }
}

// ---------------------------------------------------------------------------
// Kernel 2: out[T,H] = h @ down^T. 128x128 tiles, grid 64x16 = 1024 (4/CU).
// Same r0 schedule + BK=64 (12 K-steps) + swizzle. LDS 32 KB/block.
// ---------------------------------------------------------------------------
__global__ __launch_bounds__(256, 4) void down_kernel(
    const bf16_t* __restrict__ Hbuf,
    const bf16_t* __restrict__ Wd,
    float* __restrict__ Out)
{
    __shared__ __align__(16) bf16_t sA[128 * 64];   // 16 KB
    __shared__ __align__(16) bf16_t sB[128 * 64];   // 16 KB

    const int tid   = threadIdx.x;
    const int lane  = tid & 63;
    const int wave  = tid >> 6;
    const int waveM = wave >> 1;
    const int waveN = wave & 1;
    const int quad  = lane >> 4;
    const int lrow  = lane & 15;

    const int blockM = blockIdx.x;    // 0..63  (T/128)
    const int blockN = blockIdx.y;    // 0..15  (H/128)

    f32x4 acc[4][4];
#pragma unroll
    for (int i = 0; i < 4; i++)
#pragma unroll
        for (int j = 0; j < 4; j++) acc[i][j] = (f32x4)(0.f);

    const bf16_t* Ab = Hbuf + (size_t)(blockM * 128) * I_DIM;
    const bf16_t* Bb = Wd   + (size_t)(blockN * 128) * I_DIM;

    int gRow[4], gCol[4];   // staging source per segment (shared by A and B)
#pragma unroll
    for (int i = 0; i < 4; i++) {
        int s = tid + 256 * i;
        gRow[i] = s >> 3;
        gCol[i] = ((s & 7) ^ ((s >> 3) & 7)) * 8;
    }

    int aOff[4], bOff[4];
#pragma unroll
    for (int mi = 0; mi < 4; mi++) {
        int r = waveM * 64 + mi * 16 + lrow;
        aOff[mi] = r * 64 + ((quad ^ (r & 7)) * 8);
    }
#pragma unroll
    for (int ni = 0; ni < 4; ni++) {
        int r = waveN * 64 + ni * 16 + lrow;
        bOff[ni] = r * 64 + ((quad ^ (r & 7)) * 8);
    }

    for (int k0 = 0; k0 < I_DIM; k0 += 64) {
#pragma unroll
        for (int i = 0; i < 4; i++) {
            async_load16(Ab + (size_t)gRow[i] * I_DIM + k0 + gCol[i],
                         &sA[(tid + 256 * i) * 8]);
            async_load16(Bb + (size_t)gRow[i] * I_DIM + k0 + gCol[i],
                         &sB[(tid + 256 * i) * 8]);
        }
        __syncthreads();

#pragma unroll
        for (int kk = 0; kk < 2; kk++) {
            const int kx = kk * 32;
            bf16x8 aF[4], bF[4];
#pragma unroll
            for (int mi = 0; mi < 4; mi++)
                aF[mi] = *(const bf16x8*)&sA[aOff[mi] ^ kx];
#pragma unroll
            for (int ni = 0; ni < 4; ni++)
                bF[ni] = *(const bf16x8*)&sB[bOff[ni] ^ kx];
#pragma unroll
            for (int mi = 0; mi < 4; mi++)
#pragma unroll
                for (int ni = 0; ni < 4; ni++)
                    acc[mi][ni] = __builtin_amdgcn_mfma_f32_16x16x32_bf16(aF[mi], bF[ni], acc[mi][ni], 0, 0, 0);
        }
        __syncthreads();
    }

#pragma unroll
    for (int mi = 0; mi < 4; mi++) {
#pragma unroll
        for (int ni = 0; ni < 4; ni++) {
#pragma unroll
            for (int r = 0; r < 4; r++) {
                int row = blockM * 128 + waveM * 64 + mi * 16 + quad * 4 + r;
                int col = blockN * 128 + waveN * 64 + ni * 16 + lrow;
                Out[(size_t)row * H_DIM + col] = acc[mi][ni][r];
            }
        }
    }
}

extern "C" void kernel_launch(void* const* d_in, const int* in_sizes, int n_in,
                              void* d_out, int out_size, void* d_ws, size_t ws_size,
                              hipStream_t stream) {
    const float* x  = (const float*)d_in[0];  // [T, H] fp32
    const float* gw = (const float*)d_in[1];  // [I, H] fp32
    const float* uw = (const float*)d_in[2];  // [I, H] fp32
    const float* dw = (const float*)d_in[3];  // [H, I] fp32
    float* out = (float*)d_out;               // [T, H] fp32

    bf16_t* xb = (bf16_t*)d_ws;
    bf16_t* gb = xb + (size_t)T_DIM * H_DIM;
    bf16_t* ub = gb + (size_t)I_DIM * H_DIM;
    bf16_t* db = ub + (size_t)I_DIM * H_DIM;
    bf16_t* hb = db + (size_t)I_DIM * H_DIM;

    cvt_kernel<<<2048, 256, 0, stream>>>(x, gw, uw, dw, xb, gb, ub, db);
    gateup_kernel<<<dim3(T_DIM / 128, I_DIM / 64), 256, 0, stream>>>(xb, gb, ub, hb);
    down_kernel<<<dim3(T_DIM / 128, H_DIM / 128), 256, 0, stream>>>(hb, db, out);
}

// Round 3
// 223.208 us; speedup vs baseline: 1.1254x; 1.0679x over previous
//
#include <hip/hip_runtime.h>
#include <hip/hip_bf16.h>
#include <stdint.h>

// Problem dims: T=8192 tokens, H=2048 hidden, I=768 intermediate
// fp32 in/out; internal bf16 MFMA (absmax 0.0156 vs 0.074 budget).
#define T_DIM 8192
#define H_DIM 2048
#define I_DIM 768

typedef __bf16 bf16_t;
typedef bf16_t bf16x8 __attribute__((ext_vector_type(8)));
typedef bf16_t bf16x4 __attribute__((ext_vector_type(4)));
typedef float  f32x4  __attribute__((ext_vector_type(4)));

// Async global->LDS, 16B per lane. LDS dest must be wave-uniform base + lane*16
// (linear). Any swizzle goes on the GLOBAL source + the ds_read address.
__device__ __forceinline__ void async_load16(const void* g, void* s) {
    __builtin_amdgcn_global_load_lds(
        (const __attribute__((address_space(1))) void*)g,
        (__attribute__((address_space(3))) void*)s, 16, 0, 0);
}

// ---------------------------------------------------------------------------
// Kernel 0: fp32 -> bf16 conversion of all four inputs into workspace.
// 8 floats/thread: 2x float4 read (32B), 1x bf16x8 write (16B).  (R2 version)
// ---------------------------------------------------------------------------
__global__ __launch_bounds__(256) void cvt_kernel(
    const float* __restrict__ X, const float* __restrict__ G,
    const float* __restrict__ U, const float* __restrict__ D,
    bf16_t* __restrict__ Xb, bf16_t* __restrict__ Gb,
    bf16_t* __restrict__ Ub, bf16_t* __restrict__ Db)
{
    const size_t N8X = (size_t)T_DIM * H_DIM / 8;
    const size_t N8W = (size_t)I_DIM * H_DIM / 8;
    const size_t total = N8X + 3 * N8W;
    for (size_t i = (size_t)blockIdx.x * blockDim.x + threadIdx.x; i < total;
         i += (size_t)gridDim.x * blockDim.x) {
        const float* s; bf16_t* d; size_t j = i;
        if (j < N8X) { s = X; d = Xb; }
        else {
            j -= N8X;
            if (j < N8W) { s = G; d = Gb; }
            else { j -= N8W;
                if (j < N8W) { s = U; d = Ub; }
                else { j -= N8W; s = D; d = Db; } }
        }
        float4 v0 = ((const float4*)s)[2 * j];
        float4 v1 = ((const float4*)s)[2 * j + 1];
        bf16x8 o;
        o[0] = (bf16_t)v0.x; o[1] = (bf16_t)v0.y; o[2] = (bf16_t)v0.z; o[3] = (bf16_t)v0.w;
        o[4] = (bf16_t)v1.x; o[5] = (bf16_t)v1.y; o[6] = (bf16_t)v1.z; o[7] = (bf16_t)v1.w;
        ((bf16x8*)d)[j] = o;
    }
}

// ---------------------------------------------------------------------------
// Kernel 1 (EXACT r0 restore -- proven 66 us): 128x64 (MxN) tile of [T, I]:
// G = x@gate^T, U = x@up^T via MFMA, h = silu(G)*U -> bf16 workspace.
// Grid 64x12 = 768 blocks = 3/CU. Block = 256 threads, 4 waves 2x2;
// wave owns 64x32 of both G and U. Single LDS buffer, plain __syncthreads.
// Schedule perturbations measured worse: dbuf+vmcnt(4) = 87 us (R1),
// BK=64 = 80 us (R2). Bank conflicts (4 cyc/ds_read) proven off-critical-path.
// ---------------------------------------------------------------------------
__global__ __launch_bounds__(256) void gateup_kernel(
    const bf16_t* __restrict__ X,
    const bf16_t* __restrict__ Wg,
    const bf16_t* __restrict__ Wu,
    bf16_t* __restrict__ Hbuf)
{
    __shared__ __align__(16) bf16_t sA[128 * 32];   // x tile       8 KB
    __shared__ __align__(16) bf16_t sG[64 * 32];    // gate_w tile  4 KB
    __shared__ __align__(16) bf16_t sU[64 * 32];    // up_w tile    4 KB

    const int tid   = threadIdx.x;
    const int lane  = tid & 63;
    const int wave  = tid >> 6;
    const int waveM = wave >> 1;      // 0..1 -> 64-row half
    const int waveN = wave & 1;       // 0..1 -> 32-col half
    const int quad  = lane >> 4;      // 0..3
    const int lrow  = lane & 15;      // 0..15

    const int blockM = blockIdx.x;    // 0..63  (T/128)
    const int blockN = blockIdx.y;    // 0..11  (I/64)

    f32x4 accG[4][2], accU[4][2];
#pragma unroll
    for (int i = 0; i < 4; i++)
#pragma unroll
        for (int j = 0; j < 2; j++) { accG[i][j] = (f32x4)(0.f); accU[i][j] = (f32x4)(0.f); }

    // A: 128x32 = 512 x 16B segments (2/thread); W: 64x32 = 256 segments (1/thread).
    // Segment s covers row = s/4, cols (s%4)*8 .. +7.
    const int s0 = tid, s1 = tid + 256;
    const int rA0 = s0 >> 2, cA0 = (s0 & 3) * 8;
    const int rA1 = s1 >> 2, cA1 = (s1 & 3) * 8;
    const int rW  = tid >> 2, cW  = (tid & 3) * 8;

    const bf16_t* Ab = X  + (size_t)(blockM * 128) * H_DIM;
    const bf16_t* Gb = Wg + (size_t)(blockN * 64) * H_DIM;
    const bf16_t* Ub = Wu + (size_t)(blockN * 64) * H_DIM;

    for (int k0 = 0; k0 < H_DIM; k0 += 32) {
        async_load16(Ab + (size_t)rA0 * H_DIM + k0 + cA0, &sA[s0 * 8]);
        async_load16(Ab + (size_t)rA1 * H_DIM + k0 + cA1, &sA[s1 * 8]);
        async_load16(Gb + (size_t)rW  * H_DIM + k0 + cW,  &sG[tid * 8]);
        async_load16(Ub + (size_t)rW  * H_DIM + k0 + cW,  &sU[tid * 8]);
        __syncthreads();   // vmcnt(0) drain + barrier

        bf16x8 aF[4], gF[2], uF[2];
#pragma unroll
        for (int mi = 0; mi < 4; mi++) {
            int r = waveM * 64 + mi * 16 + lrow;
            aF[mi] = *(const bf16x8*)&sA[r * 32 + quad * 8];
        }
#pragma unroll
        for (int ni = 0; ni < 2; ni++) {
            int r = waveN * 32 + ni * 16 + lrow;
            gF[ni] = *(const bf16x8*)&sG[r * 32 + quad * 8];
            uF[ni] = *(const bf16x8*)&sU[r * 32 + quad * 8];
        }
        __syncthreads();   // frags in regs; next iter overwrites LDS

#pragma unroll
        for (int mi = 0; mi < 4; mi++)
#pragma unroll
            for (int ni = 0; ni < 2; ni++) {
                accG[mi][ni] = __builtin_amdgcn_mfma_f32_16x16x32_bf16(aF[mi], gF[ni], accG[mi][ni], 0, 0, 0);
                accU[mi][ni] = __builtin_amdgcn_mfma_f32_16x16x32_bf16(aF[mi], uF[ni], accU[mi][ni], 0, 0, 0);
            }
    }

    // Epilogue: h = silu(g)*u, cast bf16. C/D layout: col=lane&15, row=quad*4+r.
#pragma unroll
    for (int mi = 0; mi < 4; mi++) {
#pragma unroll
        for (int ni = 0; ni < 2; ni++) {
#pragma unroll
            for (int r = 0; r < 4; r++) {
                int row = blockM * 128 + waveM * 64 + mi * 16 + quad * 4 + r;
                int col = blockN * 64 + waveN * 32 + ni * 16 + lrow;
                float g = accG[mi][ni][r];
                float u = accU[mi][ni][r];
                float h = (g / (1.f + __expf(-g))) * u;
                Hbuf[(size_t)row * I_DIM + col] = (bf16_t)h;
            }
        }
    }
}

// ---------------------------------------------------------------------------
// Kernel 2 (R2 version, kept): out[T,H] = h @ down^T. 128x128 tiles,
// grid 64x16 = 1024 (4/CU), BK=64 (12 K-steps), XOR LDS swizzle.
// R2's non-gateup time was 6.6 us better than r0's with this version.
// ---------------------------------------------------------------------------
__global__ __launch_bounds__(256, 4) void down_kernel(
    const bf16_t* __restrict__ Hbuf,
    const bf16_t* __restrict__ Wd,
    float* __restrict__ Out)
{
    __shared__ __align__(16) bf16_t sA[128 * 64];   // 16 KB
    __shared__ __align__(16) bf16_t sB[128 * 64];   // 16 KB

    const int tid   = threadIdx.x;
    const int lane  = tid & 63;
    const int wave  = tid >> 6;
    const int waveM = wave >> 1;
    const int waveN = wave & 1;
    const int quad  = lane >> 4;
    const int lrow  = lane & 15;

    const int blockM = blockIdx.x;    // 0..63  (T/128)
    const int blockN = blockIdx.y;    // 0..15  (H/128)

    f32x4 acc[4][4];
#pragma unroll
    for (int i = 0; i < 4; i++)
#pragma unroll
        for (int j = 0; j < 4; j++) acc[i][j] = (f32x4)(0.f);

    const bf16_t* Ab = Hbuf + (size_t)(blockM * 128) * I_DIM;
    const bf16_t* Bb = Wd   + (size_t)(blockN * 128) * I_DIM;

    int gRow[4], gCol[4];   // staging source per segment (shared by A and B)
#pragma unroll
    for (int i = 0; i < 4; i++) {
        int s = tid + 256 * i;
        gRow[i] = s >> 3;
        gCol[i] = ((s & 7) ^ ((s >> 3) & 7)) * 8;
    }

    int aOff[4], bOff[4];
#pragma unroll
    for (int mi = 0; mi < 4; mi++) {
        int r = waveM * 64 + mi * 16 + lrow;
        aOff[mi] = r * 64 + ((quad ^ (r & 7)) * 8);
    }
#pragma unroll
    for (int ni = 0; ni < 4; ni++) {
        int r = waveN * 64 + ni * 16 + lrow;
        bOff[ni] = r * 64 + ((quad ^ (r & 7)) * 8);
    }

    for (int k0 = 0; k0 < I_DIM; k0 += 64) {
#pragma unroll
        for (int i = 0; i < 4; i++) {
            async_load16(Ab + (size_t)gRow[i] * I_DIM + k0 + gCol[i],
                         &sA[(tid + 256 * i) * 8]);
            async_load16(Bb + (size_t)gRow[i] * I_DIM + k0 + gCol[i],
                         &sB[(tid + 256 * i) * 8]);
        }
        __syncthreads();

#pragma unroll
        for (int kk = 0; kk < 2; kk++) {
            const int kx = kk * 32;   // slot^4 <=> element offset ^32
            bf16x8 aF[4], bF[4];
#pragma unroll
            for (int mi = 0; mi < 4; mi++)
                aF[mi] = *(const bf16x8*)&sA[aOff[mi] ^ kx];
#pragma unroll
            for (int ni = 0; ni < 4; ni++)
                bF[ni] = *(const bf16x8*)&sB[bOff[ni] ^ kx];
#pragma unroll
            for (int mi = 0; mi < 4; mi++)
#pragma unroll
                for (int ni = 0; ni < 4; ni++)
                    acc[mi][ni] = __builtin_amdgcn_mfma_f32_16x16x32_bf16(aF[mi], bF[ni], acc[mi][ni], 0, 0, 0);
        }
        __syncthreads();
    }

#pragma unroll
    for (int mi = 0; mi < 4; mi++) {
#pragma unroll
        for (int ni = 0; ni < 4; ni++) {
#pragma unroll
            for (int r = 0; r < 4; r++) {
                int row = blockM * 128 + waveM * 64 + mi * 16 + quad * 4 + r;
                int col = blockN * 128 + waveN * 64 + ni * 16 + lrow;
                Out[(size_t)row * H_DIM + col] = acc[mi][ni][r];
            }
        }
    }
}

extern "C" void kernel_launch(void* const* d_in, const int* in_sizes, int n_in,
                              void* d_out, int out_size, void* d_ws, size_t ws_size,
                              hipStream_t stream) {
    const float* x  = (const float*)d_in[0];  // [T, H] fp32
    const float* gw = (const float*)d_in[1];  // [I, H] fp32
    const float* uw = (const float*)d_in[2];  // [I, H] fp32
    const float* dw = (const float*)d_in[3];  // [H, I] fp32
    float* out = (float*)d_out;               // [T, H] fp32

    bf16_t* xb = (bf16_t*)d_ws;
    bf16_t* gb = xb + (size_t)T_DIM * H_DIM;
    bf16_t* ub = gb + (size_t)I_DIM * H_DIM;
    bf16_t* db = ub + (size_t)I_DIM * H_DIM;
    bf16_t* hb = db + (size_t)I_DIM * H_DIM;

    cvt_kernel<<<2048, 256, 0, stream>>>(x, gw, uw, dw, xb, gb, ub, db);
    gateup_kernel<<<dim3(T_DIM / 128, I_DIM / 64), 256, 0, stream>>>(xb, gb, ub, hb);
    down_kernel<<<dim3(T_DIM / 128, H_DIM / 128), 256, 0, stream>>>(hb, db, out);
}